// Round 15
// baseline (117.910 us; speedup 1.0000x reference)
//
#include <hip/hip_runtime.h>
#include <hip/hip_fp16.h>

// out[b, m, r] = x[b, ind[r,m]] * filters[r, ind[r,m]]
// rem = m*512+r; out flat = b*65536 + rem.
//
// map14 = map13 (1 row/block, grid=1024, LDS fp16 row, inter-block overlap)
// + latency shaving:
//  - pk groups 0,1 issued BEFORE the stage (oldest in vmcnt queue: their
//    waits never drain stage loads; L2 latency hides under stage).
//  - stage software-pipelined 1 load-group ahead (16 VGPR) so the final
//    ds_write isn't stalled on a freshly-issued HBM load.
//  - compute fully unrolled with a 2-deep pk pipeline: every pk wait is
//    >=2 groups old (already landed), never behind the output stores.

constexpr int D_ROW = 128;
constexpr int D_COL = 512;
constexpr int D_ALL = D_ROW * D_COL;   // 65536
constexpr int BATCH = 1024;

// pk[m*512+r] = (fp16bits(filters[r, ind[r,m]]) << 16) | ind[r,m]
__global__ void __launch_bounds__(256)
build_pk(const float* __restrict__ filters,
         const int*   __restrict__ ind,
         unsigned* __restrict__ pk) {
    int t = blockIdx.x * 256 + threadIdx.x;
    if (t >= D_ALL) return;
    int m = t >> 9, r = t & 511;
    int idx = ind[r * D_ROW + m];
    __half hw = __float2half_rn(filters[(size_t)r * D_ALL + idx]);
    pk[t] = ((unsigned)__half_as_ushort(hw) << 16) | (unsigned)idx;
}

__device__ __forceinline__ float map_one(const __half* xs, unsigned p) {
    return __half2float(xs[p & 0xffffu]) *
           __half2float(__ushort_as_half((unsigned short)(p >> 16)));
}
__device__ __forceinline__ unsigned h2bits(float a, float b) {
    __half2 h = __floats2half2_rn(a, b);
    return *reinterpret_cast<unsigned*>(&h);
}
__device__ __forceinline__ void lds_barrier() {
    asm volatile("s_waitcnt lgkmcnt(0)" ::: "memory");
    __builtin_amdgcn_s_barrier();
}

__global__ void __launch_bounds__(1024)
map14(const float* __restrict__ x,
      const uint4* __restrict__ pk4,    // pk4[j*1024 + t]
      float* __restrict__ out) {
    __shared__ __half xs[D_ALL];        // 128 KB: full row as fp16
    const int t = threadIdx.x;          // 0..1023
    const int b = blockIdx.x;           // one batch row per block

    // ---- pre-issue pk groups 0,1 (L2): oldest in vmcnt queue ----
    uint4 pA = pk4[t];
    uint4 pB = pk4[1024 + t];
    __builtin_amdgcn_sched_barrier(0);

    // ---- stage: x row -> fp16 LDS, software-pipelined 1 group ahead ----
    const float4* src = reinterpret_cast<const float4*>(x + ((size_t)b << 16));
    float4 a0 = src[t * 2];
    float4 a1 = src[t * 2 + 1];
    #pragma unroll
    for (int i = 0; i < 8; ++i) {
        float4 b0, b1;
        if (i + 1 < 8) {
            b0 = src[(i + 1) * 2048 + t * 2];
            b1 = src[(i + 1) * 2048 + t * 2 + 1];
        }
        uint4 u;
        u.x = h2bits(a0.x, a0.y);
        u.y = h2bits(a0.z, a0.w);
        u.z = h2bits(a1.x, a1.y);
        u.w = h2bits(a1.z, a1.w);
        *reinterpret_cast<uint4*>(xs + (size_t)(i * 2048 + t * 2) * 4) = u;
        a0 = b0; a1 = b1;
    }
    lds_barrier();

    // ---- compute: 64 outputs/thread, 2-deep pk pipeline, full unroll ----
    float* ob = out + ((size_t)b << 16);
    #pragma unroll
    for (int j = 0; j < 16; ++j) {
        uint4 cur = pA;
        pA = pB;
        if (j + 2 < 16) pB = pk4[(j + 2) * 1024 + t];   // issue before stores
        float4 r;
        r.x = map_one(xs, cur.x);
        r.y = map_one(xs, cur.y);
        r.z = map_one(xs, cur.z);
        r.w = map_one(xs, cur.w);
        *reinterpret_cast<float4*>(ob + j * 4096 + t * 4) = r;
    }
}

// ---------------- fallback: direct gather (correct, slow) ----------------
__global__ void __launch_bounds__(256)
map_kernel_nows(const float* __restrict__ x,
                const float* __restrict__ filters,
                const int*   __restrict__ ind,
                float*       __restrict__ out) {
    size_t o = (size_t)blockIdx.x * 256 + threadIdx.x;
    if (o >= (size_t)BATCH * D_ALL) return;
    unsigned b = (unsigned)(o >> 16);
    unsigned rem = (unsigned)(o & 65535u);
    unsigned m = rem >> 9, r = rem & 511u;
    int idx = ind[r * D_ROW + m];
    out[o] = x[((size_t)b << 16) + idx] * filters[(size_t)r * D_ALL + idx];
}

extern "C" void kernel_launch(void* const* d_in, const int* in_sizes, int n_in,
                              void* d_out, int out_size, void* d_ws, size_t ws_size,
                              hipStream_t stream) {
    const float* x       = (const float*)d_in[0];
    const float* filters = (const float*)d_in[1];
    const int*   ind     = (const int*)d_in[2];
    float*       out     = (float*)d_out;

    const size_t need = (size_t)D_ALL * sizeof(unsigned);   // 256 KB
    if (ws_size >= need) {
        unsigned* pk = (unsigned*)d_ws;
        build_pk<<<D_ALL / 256, 256, 0, stream>>>(filters, ind, pk);
        map14<<<BATCH, 1024, 0, stream>>>(
            x, reinterpret_cast<const uint4*>(pk), out);
    } else {
        map_kernel_nows<<<(BATCH * (size_t)D_ALL) / 256, 256, 0, stream>>>(
            x, filters, ind, out);
    }
}